// Round 5
// baseline (447.712 us; speedup 1.0000x reference)
//
#include <hip/hip_runtime.h>

// GCN 2-layer forward on MI355X (gfx950).
// R5: replace atomic counting-sort CSR build (k_count+k_fill, ~65us, 52MB
// write-amplified scatter) with binned two-pass build:
//   k_bin   : bucket edges by dst>>7 into 391 dense streams (4B packed)
//   k_hist  : per-bucket LDS histogram -> deg/dinv (no global atomics)
//   k_place : per-bucket LDS cursors -> csr (contiguous region per WG)
// k_gemm1 / k_layer1 / k_layer2_pool unchanged from R4.

#define NGRAPH 64
#define CH 128
#define BCAP 2560   // bucket capacity: lambda=2048, +11 sigma

typedef float f32x4 __attribute__((ext_vector_type(4)));
typedef _Float16 f16x8 __attribute__((ext_vector_type(8)));
typedef _Float16 f16x4 __attribute__((ext_vector_type(4)));
typedef _Float16 f16x2 __attribute__((ext_vector_type(2)));

// ---------------- init ----------------
__global__ void k_init(int* __restrict__ bcur, int* __restrict__ row_start,
                       float* __restrict__ gsum, int* __restrict__ gcnt,
                       int NB, int N, int E) {
    int i = blockIdx.x * blockDim.x + threadIdx.x;
    if (i < NB) bcur[i] = 0;
    if (i == 0) row_start[N] = E;          // sentinel (non-self edge total)
    if (i < 2 * NGRAPH) gsum[i] = 0.f;
    if (i < NGRAPH) gcnt[i] = 0;
}

// ---------------- pass 1: bin edges by dst>>7 ----------------
__global__ void k_bin(const int* __restrict__ src, const int* __restrict__ dst,
                      int* __restrict__ bcur, unsigned int* __restrict__ tmp, int E) {
    int i = blockIdx.x * blockDim.x + threadIdx.x;
    if (i < E) {
        int d = dst[i];
        int b = d >> 7;
        int pos = atomicAdd(&bcur[b], 1);
        if (pos < BCAP)
            tmp[(size_t)b * BCAP + pos] = ((unsigned)(d & 127) << 25) | (unsigned)src[i];
    }
}

// ---------------- pass 2a: per-bucket LDS histogram -> deg, dinv ----------------
__global__ __launch_bounds__(256) void k_hist(const unsigned int* __restrict__ tmp,
                                              const int* __restrict__ bcur,
                                              int* __restrict__ deg,
                                              float* __restrict__ dinv, int N) {
    __shared__ int hist[128];
    int b = blockIdx.x, t = threadIdx.x;
    if (t < 128) hist[t] = 0;
    __syncthreads();
    int cnt = min(bcur[b], BCAP);
    const unsigned int* tp = tmp + (size_t)b * BCAP;
    for (int e = t; e < cnt; e += 256) atomicAdd(&hist[tp[e] >> 25], 1);
    __syncthreads();
    int n = b * 128 + t;
    if (t < 128 && n < N) {
        int d = hist[t] + 1;               // + self-loop
        deg[n] = d;
        dinv[n] = rsqrtf((float)d);
    }
}

// ---------------- exclusive scan of (deg-1) over N elements, 3 passes ----------------
__global__ void k_scan_a(const int* __restrict__ deg, int* __restrict__ row_start,
                         int* __restrict__ bsum, int N) {
    __shared__ int tmp[256];
    int t = threadIdx.x;
    int i = blockIdx.x * 256 + t;
    int v = (i < N) ? (deg[i] - 1) : 0;   // edges excluding self-loop
    int val = v;
    tmp[t] = val;
    __syncthreads();
    for (int off = 1; off < 256; off <<= 1) {
        int add = (t >= off) ? tmp[t - off] : 0;
        __syncthreads();
        val += add;
        tmp[t] = val;
        __syncthreads();
    }
    if (i < N) row_start[i] = val - v;     // exclusive
    if (t == 255) bsum[blockIdx.x] = val;  // block total
}

__global__ void k_scan_b(const int* __restrict__ bsum, int* __restrict__ boff, int nb) {
    __shared__ int tmp[256];
    int t = threadIdx.x;
    int v = (t < nb) ? bsum[t] : 0;
    int val = v;
    tmp[t] = val;
    __syncthreads();
    for (int off = 1; off < 256; off <<= 1) {
        int add = (t >= off) ? tmp[t - off] : 0;
        __syncthreads();
        val += add;
        tmp[t] = val;
        __syncthreads();
    }
    if (t < nb) boff[t] = val - v;
}

__global__ void k_scan_c(int* __restrict__ row_start, const int* __restrict__ boff, int N) {
    int i = blockIdx.x * blockDim.x + threadIdx.x;
    if (i < N) row_start[i] += boff[blockIdx.x];
}

// ---------------- pass 2b: per-bucket LDS cursors -> csr ----------------
__global__ __launch_bounds__(256) void k_place(const unsigned int* __restrict__ tmp,
                                               const int* __restrict__ bcur,
                                               const int* __restrict__ row_start,
                                               int* __restrict__ csr, int N) {
    __shared__ int lcur[128];
    int b = blockIdx.x, t = threadIdx.x;
    int nb0 = b * 128;
    int base = row_start[nb0];             // uniform (nb0 < N for all buckets)
    if (t < 128) {
        int n = nb0 + t;
        lcur[t] = ((n < N) ? row_start[n] : 0) - base;
    }
    __syncthreads();
    int cnt = min(bcur[b], BCAP);
    const unsigned int* tp = tmp + (size_t)b * BCAP;
    for (int e = t; e < cnt; e += 256) {
        unsigned p = tp[e];
        int pos = atomicAdd(&lcur[p >> 25], 1);   // LDS atomic
        csr[base + pos] = (int)(p & 0x01FFFFFFu);
    }
}

// ---------------- GEMM1 (MFMA fp16): h[n] = fp16((x[n] @ W1) * dinv[n]) ----------------
__global__ __launch_bounds__(256) void k_gemm1(const float* __restrict__ X,
                                               const float* __restrict__ W1,
                                               const float* __restrict__ dinv,
                                               _Float16* __restrict__ H, int N) {
    __shared__ _Float16 Xs[64 * 136];   // 272B row stride (16B-aligned)
    __shared__ _Float16 Ws[128 * 136];  // transposed: Ws[col][k]
    int t = threadIdx.x;
    int row0 = blockIdx.x * 64;
    const float4* Xv = (const float4*)X;
    const float4* Wv = (const float4*)W1;

    #pragma unroll
    for (int i = 0; i < 8; i++) {
        int gi = t + i * 256;            // 2048 float4
        int r = gi >> 5, c4 = gi & 31;
        int gr = row0 + r;
        float4 v = (gr < N) ? Xv[(size_t)gr * 32 + c4] : make_float4(0.f, 0.f, 0.f, 0.f);
        f16x4 hv = {(_Float16)v.x, (_Float16)v.y, (_Float16)v.z, (_Float16)v.w};
        *(f16x4*)&Xs[r * 136 + 4 * c4] = hv;
    }
    #pragma unroll
    for (int i = 0; i < 4; i++) {
        int b = t + i * 256;             // 1024 4x4 blocks
        int kb = b >> 5, cb = b & 31;
        float4 r0 = Wv[(4 * kb + 0) * 32 + cb];
        float4 r1 = Wv[(4 * kb + 1) * 32 + cb];
        float4 r2 = Wv[(4 * kb + 2) * 32 + cb];
        float4 r3 = Wv[(4 * kb + 3) * 32 + cb];
        f16x4 c0v = {(_Float16)r0.x, (_Float16)r1.x, (_Float16)r2.x, (_Float16)r3.x};
        f16x4 c1v = {(_Float16)r0.y, (_Float16)r1.y, (_Float16)r2.y, (_Float16)r3.y};
        f16x4 c2v = {(_Float16)r0.z, (_Float16)r1.z, (_Float16)r2.z, (_Float16)r3.z};
        f16x4 c3v = {(_Float16)r0.w, (_Float16)r1.w, (_Float16)r2.w, (_Float16)r3.w};
        *(f16x4*)&Ws[(4 * cb + 0) * 136 + 4 * kb] = c0v;
        *(f16x4*)&Ws[(4 * cb + 1) * 136 + 4 * kb] = c1v;
        *(f16x4*)&Ws[(4 * cb + 2) * 136 + 4 * kb] = c2v;
        *(f16x4*)&Ws[(4 * cb + 3) * 136 + 4 * kb] = c3v;
    }
    __syncthreads();

    int w = t >> 6, l = t & 63;
    int r0w = w * 16;
    int lr = l & 15, lk = (l >> 4) * 8;
    f32x4 acc[8] = {};
    #pragma unroll
    for (int k0 = 0; k0 < 128; k0 += 32) {
        f16x8 a = *(const f16x8*)&Xs[(r0w + lr) * 136 + k0 + lk];
        #pragma unroll
        for (int c = 0; c < 8; c++) {
            f16x8 bf = *(const f16x8*)&Ws[(c * 16 + lr) * 136 + k0 + lk];
            acc[c] = __builtin_amdgcn_mfma_f32_16x16x32_f16(a, bf, acc[c], 0, 0, 0);
        }
    }
    float dv[4];
    #pragma unroll
    for (int q = 0; q < 4; q++) {
        int gr = row0 + r0w + (l >> 4) * 4 + q;
        dv[q] = (gr < N) ? dinv[gr] : 0.f;
    }
    __syncthreads();
    #pragma unroll
    for (int c = 0; c < 8; c++)
        #pragma unroll
        for (int q = 0; q < 4; q++)      // C/D map: col=lane&15, row=(lane>>4)*4+q
            Xs[(r0w + (l >> 4) * 4 + q) * 136 + c * 16 + lr] = (_Float16)(acc[c][q] * dv[q]);
    __syncthreads();
    f16x2* Hv = (f16x2*)H;
    #pragma unroll
    for (int i = 0; i < 16; i++) {
        int gi = t + i * 256;            // 4096 half2
        int r = gi >> 6, cp = gi & 63;
        int gr = row0 + r;
        if (gr < N) Hv[(size_t)gr * 64 + cp] = *(f16x2*)&Xs[r * 136 + 2 * cp];
    }
}

// ---------------- layer1 aggregate + bias + relu + GEMM2 fused ----------------
// one WAVE per node; lane l = channels 2l,2l+1. Gather unrolled x8 for MLP.
__global__ __launch_bounds__(256) void k_layer1(const _Float16* __restrict__ h,
                                                const int* __restrict__ csr,
                                                const int* __restrict__ row_start,
                                                const float* __restrict__ dinv,
                                                const float* __restrict__ b1,
                                                const float* __restrict__ W2,
                                                float* __restrict__ h2, int N) {
    int n = (blockIdx.x * 256 + threadIdx.x) >> 6;
    int l = threadIdx.x & 63;
    if (n >= N) return;
    const f16x2* hv = (const f16x2*)h;
    float dn = dinv[n];
    f16x2 self = hv[(size_t)n * 64 + l];
    float acc0 = (float)self.x, acc1 = (float)self.y;
    int base = row_start[n];
    int cnt = row_start[n + 1] - base;
    for (int c0 = 0; c0 < cnt; c0 += 64) {
        int m = cnt - c0; if (m > 64) m = 64;
        int idx = (c0 + l < cnt) ? csr[base + c0 + l] : 0;
        int j = 0;
        int jm = m & ~7;
        for (; j < jm; j += 8) {         // 8 independent 256B row-gathers in flight
            int s0 = __shfl(idx, j + 0), s1 = __shfl(idx, j + 1);
            int s2 = __shfl(idx, j + 2), s3 = __shfl(idx, j + 3);
            int s4 = __shfl(idx, j + 4), s5 = __shfl(idx, j + 5);
            int s6 = __shfl(idx, j + 6), s7 = __shfl(idx, j + 7);
            f16x2 v0 = hv[(size_t)s0 * 64 + l];
            f16x2 v1 = hv[(size_t)s1 * 64 + l];
            f16x2 v2 = hv[(size_t)s2 * 64 + l];
            f16x2 v3 = hv[(size_t)s3 * 64 + l];
            f16x2 v4 = hv[(size_t)s4 * 64 + l];
            f16x2 v5 = hv[(size_t)s5 * 64 + l];
            f16x2 v6 = hv[(size_t)s6 * 64 + l];
            f16x2 v7 = hv[(size_t)s7 * 64 + l];
            acc0 += (float)v0.x; acc1 += (float)v0.y;
            acc0 += (float)v1.x; acc1 += (float)v1.y;
            acc0 += (float)v2.x; acc1 += (float)v2.y;
            acc0 += (float)v3.x; acc1 += (float)v3.y;
            acc0 += (float)v4.x; acc1 += (float)v4.y;
            acc0 += (float)v5.x; acc1 += (float)v5.y;
            acc0 += (float)v6.x; acc1 += (float)v6.y;
            acc0 += (float)v7.x; acc1 += (float)v7.y;
        }
        for (; j < m; ++j) {
            int s = __shfl(idx, j);
            f16x2 v = hv[(size_t)s * 64 + l];
            acc0 += (float)v.x; acc1 += (float)v.y;
        }
    }
    float2 bb = ((const float2*)b1)[l];
    float v0 = fmaxf(fmaf(dn, acc0, bb.x), 0.f);
    float v1 = fmaxf(fmaf(dn, acc1, bb.y), 0.f);
    float4 w2 = ((const float4*)W2)[l];  // rows 2l,2l+1 of W2[128][2]
    float p0 = fmaf(v0, w2.x, v1 * w2.z);
    float p1 = fmaf(v0, w2.y, v1 * w2.w);
    #pragma unroll
    for (int off = 32; off; off >>= 1) {
        p0 += __shfl_xor(p0, off);
        p1 += __shfl_xor(p1, off);
    }
    if (l == 0) ((float2*)h2)[n] = make_float2(p0 * dn, p1 * dn);  // pre-scaled by dinv[n]
}

// ---------------- layer2 aggregate + global mean pool accumulate ----------------
__global__ __launch_bounds__(256) void k_layer2_pool(const float* __restrict__ h2,
                                                     const int* __restrict__ csr,
                                                     const int* __restrict__ row_start,
                                                     const float* __restrict__ dinv,
                                                     const int* __restrict__ batch,
                                                     float* __restrict__ gsum,
                                                     int* __restrict__ gcnt, int N) {
    __shared__ float ssum[2 * NGRAPH];
    __shared__ int scnt[NGRAPH];
    int t = threadIdx.x;
    if (t < 2 * NGRAPH) ssum[t] = 0.f;
    if (t < NGRAPH) scnt[t] = 0;
    __syncthreads();
    int n = blockIdx.x * blockDim.x + t;
    if (n < N) {
        const float2* h2v = (const float2*)h2;
        float dn = dinv[n];
        float2 a = h2v[n];               // self term (already *dinv[n])
        int base = row_start[n], end = row_start[n + 1];
        for (int e = base; e < end; e++) {
            float2 v = h2v[csr[e]];
            a.x += v.x;
            a.y += v.y;
        }
        a.x *= dn;
        a.y *= dn;
        int g = batch[n];
        atomicAdd(&ssum[g * 2 + 0], a.x);
        atomicAdd(&ssum[g * 2 + 1], a.y);
        atomicAdd(&scnt[g], 1);
    }
    __syncthreads();
    if (t < 2 * NGRAPH) atomicAdd(&gsum[t], ssum[t]);
    if (t < NGRAPH) atomicAdd(&gcnt[t], scnt[t]);
}

__global__ void k_final(const float* __restrict__ gsum, const int* __restrict__ gcnt,
                        const float* __restrict__ b2, float* __restrict__ out) {
    int t = threadIdx.x;   // 0..127
    if (t < 2 * NGRAPH) {
        int g = t >> 1, c = t & 1;
        float cnt = fmaxf((float)gcnt[g], 1.f);
        out[t] = gsum[t] / cnt + b2[c];
    }
}

extern "C" void kernel_launch(void* const* d_in, const int* in_sizes, int n_in,
                              void* d_out, int out_size, void* d_ws, size_t ws_size,
                              hipStream_t stream) {
    const float* x     = (const float*)d_in[0];
    const int*   ei    = (const int*)d_in[1];
    const int*   batch = (const int*)d_in[2];
    const float* W1    = (const float*)d_in[3];
    const float* b1    = (const float*)d_in[4];
    const float* W2    = (const float*)d_in[5];
    const float* b2    = (const float*)d_in[6];
    float* out = (float*)d_out;

    int N = in_sizes[0] / CH;    // 50000
    int E = in_sizes[1] / 2;     // 800000
    int NB = (N + 127) / 128;    // 391 buckets
    const int* esrc = ei;
    const int* edst = ei + E;

    char* w = (char*)d_ws;
    auto alloc = [&](size_t bytes) -> void* {
        void* p = (void*)w;
        w += (bytes + 255) & ~(size_t)255;
        return p;
    };
    _Float16* h      = (_Float16*)alloc((size_t)N * CH * sizeof(_Float16));  // 12.8 MB
    int* deg         = (int*)  alloc((size_t)N * sizeof(int));
    float* dinv      = (float*)alloc((size_t)N * sizeof(float));
    int* row_start   = (int*)  alloc((size_t)(N + 1) * sizeof(int));
    int* csr         = (int*)  alloc((size_t)E * sizeof(int));
    float* h2        = (float*)alloc((size_t)N * 2 * sizeof(float));
    int* bcur        = (int*)  alloc((size_t)NB * sizeof(int));
    int* bsum        = (int*)  alloc(256 * sizeof(int));
    int* boff        = (int*)  alloc(256 * sizeof(int));
    float* gsum      = (float*)alloc(128 * sizeof(float));
    int* gcnt        = (int*)  alloc(64 * sizeof(int));
    // bin buffer aliases h: tmp (4 MB) is dead before k_gemm1 writes h (stream order)
    unsigned int* tmp = (unsigned int*)h;

    int nbN = (N + 255) / 256;     // 196 (<=256 so single-block scan_b works)
    int nbE = (E + 255) / 256;

    k_init  <<<nbN, 256, 0, stream>>>(bcur, row_start, gsum, gcnt, NB, N, E);
    k_bin   <<<nbE, 256, 0, stream>>>(esrc, edst, bcur, tmp, E);
    k_hist  <<<NB,  256, 0, stream>>>(tmp, bcur, deg, dinv, N);
    k_scan_a<<<nbN, 256, 0, stream>>>(deg, row_start, bsum, N);
    k_scan_b<<<1,   256, 0, stream>>>(bsum, boff, nbN);
    k_scan_c<<<nbN, 256, 0, stream>>>(row_start, boff, N);
    k_place <<<NB,  256, 0, stream>>>(tmp, bcur, row_start, csr, N);
    k_gemm1 <<<(N + 63) / 64, 256, 0, stream>>>(x, W1, dinv, h, N);
    k_layer1<<<(N * 64 + 255) / 256, 256, 0, stream>>>(h, csr, row_start, dinv, b1, W2, h2, N);
    k_layer2_pool<<<nbN, 256, 0, stream>>>(h2, csr, row_start, dinv, batch, gsum, gcnt, N);
    k_final <<<1, 128, 0, stream>>>(gsum, gcnt, b2, out);
}

// Round 6
// 185.490 us; speedup vs baseline: 2.4137x; 2.4137x over previous
//
#include <hip/hip_runtime.h>

// GCN 2-layer forward on MI355X (gfx950).
// R6: fix R5's k_bin atomic-contention disaster (281us, 391 hot counters).
// Block-aggregated two-phase binning: per-block LDS histogram -> ONE global
// atomic per (block,bucket) into 8-way-replicated counters -> LDS-cursor
// scatter. Global atomics 800K -> ~100K, per-address depth 2048 -> 32.
// k_hist/k_place iterate the 8 sub-segments. Everything else unchanged.

#define NGRAPH 64
#define CH 128
#define BSUB 384          // per-(bucket,copy) capacity: lambda=256, +8 sigma
#define NCOPY 8
#define BCAPT (BSUB * NCOPY)   // 3072 slots per bucket

typedef float f32x4 __attribute__((ext_vector_type(4)));
typedef _Float16 f16x8 __attribute__((ext_vector_type(8)));
typedef _Float16 f16x4 __attribute__((ext_vector_type(4)));
typedef _Float16 f16x2 __attribute__((ext_vector_type(2)));

// ---------------- init ----------------
__global__ void k_init(int* __restrict__ bcur8, int* __restrict__ row_start,
                       float* __restrict__ gsum, int* __restrict__ gcnt,
                       int NB, int N, int E) {
    int i = blockIdx.x * blockDim.x + threadIdx.x;
    if (i < NB * NCOPY) bcur8[i] = 0;
    if (i == 0) row_start[N] = E;          // sentinel (non-self edge total)
    if (i < 2 * NGRAPH) gsum[i] = 0.f;
    if (i < NGRAPH) gcnt[i] = 0;
}

// ---------------- pass 1: chunked block-aggregated binning ----------------
__global__ __launch_bounds__(256) void k_bin(const int* __restrict__ src,
                                             const int* __restrict__ dst,
                                             int* __restrict__ bcur8,
                                             unsigned int* __restrict__ tmp,
                                             int E, int EPB) {
    __shared__ int hist[512];
    __shared__ int gbase[512];
    __shared__ int cur[512];
    int t = threadIdx.x;
    int e0 = blockIdx.x * EPB;
    int e1 = min(E, e0 + EPB);
    for (int i = t; i < 512; i += 256) { hist[i] = 0; cur[i] = 0; }
    __syncthreads();
    for (int e = e0 + t; e < e1; e += 256)
        atomicAdd(&hist[dst[e] >> 7], 1);          // LDS atomic, ~8 deep
    __syncthreads();
    int copy = blockIdx.x & (NCOPY - 1);
    for (int b = t; b < 512; b += 256) {
        int hc = hist[b];
        if (hc) gbase[b] = atomicAdd(&bcur8[b * NCOPY + copy], hc);  // 1 per bucket
    }
    __syncthreads();
    for (int e = e0 + t; e < e1; e += 256) {
        int d = dst[e];
        int b = d >> 7;
        int li = atomicAdd(&cur[b], 1);            // LDS cursor
        int pos = gbase[b] + li;
        if (pos < BSUB)
            tmp[(size_t)b * BCAPT + copy * BSUB + pos] =
                ((unsigned)(d & 127) << 25) | (unsigned)src[e];
    }
}

// ---------------- pass 2a: per-bucket LDS histogram -> deg, dinv ----------------
__global__ __launch_bounds__(256) void k_hist(const unsigned int* __restrict__ tmp,
                                              const int* __restrict__ bcur8,
                                              int* __restrict__ deg,
                                              float* __restrict__ dinv, int N) {
    __shared__ int hist[128];
    int b = blockIdx.x, t = threadIdx.x;
    if (t < 128) hist[t] = 0;
    __syncthreads();
    const unsigned int* tb = tmp + (size_t)b * BCAPT;
    for (int c = 0; c < NCOPY; c++) {
        int cnt = min(bcur8[b * NCOPY + c], BSUB);
        const unsigned int* tp = tb + c * BSUB;
        for (int e = t; e < cnt; e += 256) atomicAdd(&hist[tp[e] >> 25], 1);
    }
    __syncthreads();
    int n = b * 128 + t;
    if (t < 128 && n < N) {
        int d = hist[t] + 1;               // + self-loop
        deg[n] = d;
        dinv[n] = rsqrtf((float)d);
    }
}

// ---------------- exclusive scan of (deg-1) over N elements, 3 passes ----------------
__global__ void k_scan_a(const int* __restrict__ deg, int* __restrict__ row_start,
                         int* __restrict__ bsum, int N) {
    __shared__ int tmp[256];
    int t = threadIdx.x;
    int i = blockIdx.x * 256 + t;
    int v = (i < N) ? (deg[i] - 1) : 0;   // edges excluding self-loop
    int val = v;
    tmp[t] = val;
    __syncthreads();
    for (int off = 1; off < 256; off <<= 1) {
        int add = (t >= off) ? tmp[t - off] : 0;
        __syncthreads();
        val += add;
        tmp[t] = val;
        __syncthreads();
    }
    if (i < N) row_start[i] = val - v;     // exclusive
    if (t == 255) bsum[blockIdx.x] = val;  // block total
}

__global__ void k_scan_b(const int* __restrict__ bsum, int* __restrict__ boff, int nb) {
    __shared__ int tmp[256];
    int t = threadIdx.x;
    int v = (t < nb) ? bsum[t] : 0;
    int val = v;
    tmp[t] = val;
    __syncthreads();
    for (int off = 1; off < 256; off <<= 1) {
        int add = (t >= off) ? tmp[t - off] : 0;
        __syncthreads();
        val += add;
        tmp[t] = val;
        __syncthreads();
    }
    if (t < nb) boff[t] = val - v;
}

__global__ void k_scan_c(int* __restrict__ row_start, const int* __restrict__ boff, int N) {
    int i = blockIdx.x * blockDim.x + threadIdx.x;
    if (i < N) row_start[i] += boff[blockIdx.x];
}

// ---------------- pass 2b: per-bucket LDS cursors -> csr ----------------
__global__ __launch_bounds__(256) void k_place(const unsigned int* __restrict__ tmp,
                                               const int* __restrict__ bcur8,
                                               const int* __restrict__ row_start,
                                               int* __restrict__ csr, int N) {
    __shared__ int lcur[128];
    int b = blockIdx.x, t = threadIdx.x;
    int nb0 = b * 128;
    int base = row_start[nb0];             // uniform (nb0 < N for all buckets)
    if (t < 128) {
        int n = nb0 + t;
        lcur[t] = ((n < N) ? row_start[n] : 0) - base;
    }
    __syncthreads();
    const unsigned int* tb = tmp + (size_t)b * BCAPT;
    for (int c = 0; c < NCOPY; c++) {
        int cnt = min(bcur8[b * NCOPY + c], BSUB);
        const unsigned int* tp = tb + c * BSUB;
        for (int e = t; e < cnt; e += 256) {
            unsigned p = tp[e];
            int pos = atomicAdd(&lcur[p >> 25], 1);   // LDS atomic
            csr[base + pos] = (int)(p & 0x01FFFFFFu);
        }
    }
}

// ---------------- GEMM1 (MFMA fp16): h[n] = fp16((x[n] @ W1) * dinv[n]) ----------------
__global__ __launch_bounds__(256) void k_gemm1(const float* __restrict__ X,
                                               const float* __restrict__ W1,
                                               const float* __restrict__ dinv,
                                               _Float16* __restrict__ H, int N) {
    __shared__ _Float16 Xs[64 * 136];   // 272B row stride (16B-aligned)
    __shared__ _Float16 Ws[128 * 136];  // transposed: Ws[col][k]
    int t = threadIdx.x;
    int row0 = blockIdx.x * 64;
    const float4* Xv = (const float4*)X;
    const float4* Wv = (const float4*)W1;

    #pragma unroll
    for (int i = 0; i < 8; i++) {
        int gi = t + i * 256;            // 2048 float4
        int r = gi >> 5, c4 = gi & 31;
        int gr = row0 + r;
        float4 v = (gr < N) ? Xv[(size_t)gr * 32 + c4] : make_float4(0.f, 0.f, 0.f, 0.f);
        f16x4 hv = {(_Float16)v.x, (_Float16)v.y, (_Float16)v.z, (_Float16)v.w};
        *(f16x4*)&Xs[r * 136 + 4 * c4] = hv;
    }
    #pragma unroll
    for (int i = 0; i < 4; i++) {
        int b = t + i * 256;             // 1024 4x4 blocks
        int kb = b >> 5, cb = b & 31;
        float4 r0 = Wv[(4 * kb + 0) * 32 + cb];
        float4 r1 = Wv[(4 * kb + 1) * 32 + cb];
        float4 r2 = Wv[(4 * kb + 2) * 32 + cb];
        float4 r3 = Wv[(4 * kb + 3) * 32 + cb];
        f16x4 c0v = {(_Float16)r0.x, (_Float16)r1.x, (_Float16)r2.x, (_Float16)r3.x};
        f16x4 c1v = {(_Float16)r0.y, (_Float16)r1.y, (_Float16)r2.y, (_Float16)r3.y};
        f16x4 c2v = {(_Float16)r0.z, (_Float16)r1.z, (_Float16)r2.z, (_Float16)r3.z};
        f16x4 c3v = {(_Float16)r0.w, (_Float16)r1.w, (_Float16)r2.w, (_Float16)r3.w};
        *(f16x4*)&Ws[(4 * cb + 0) * 136 + 4 * kb] = c0v;
        *(f16x4*)&Ws[(4 * cb + 1) * 136 + 4 * kb] = c1v;
        *(f16x4*)&Ws[(4 * cb + 2) * 136 + 4 * kb] = c2v;
        *(f16x4*)&Ws[(4 * cb + 3) * 136 + 4 * kb] = c3v;
    }
    __syncthreads();

    int w = t >> 6, l = t & 63;
    int r0w = w * 16;
    int lr = l & 15, lk = (l >> 4) * 8;
    f32x4 acc[8] = {};
    #pragma unroll
    for (int k0 = 0; k0 < 128; k0 += 32) {
        f16x8 a = *(const f16x8*)&Xs[(r0w + lr) * 136 + k0 + lk];
        #pragma unroll
        for (int c = 0; c < 8; c++) {
            f16x8 bf = *(const f16x8*)&Ws[(c * 16 + lr) * 136 + k0 + lk];
            acc[c] = __builtin_amdgcn_mfma_f32_16x16x32_f16(a, bf, acc[c], 0, 0, 0);
        }
    }
    float dv[4];
    #pragma unroll
    for (int q = 0; q < 4; q++) {
        int gr = row0 + r0w + (l >> 4) * 4 + q;
        dv[q] = (gr < N) ? dinv[gr] : 0.f;
    }
    __syncthreads();
    #pragma unroll
    for (int c = 0; c < 8; c++)
        #pragma unroll
        for (int q = 0; q < 4; q++)      // C/D map: col=lane&15, row=(lane>>4)*4+q
            Xs[(r0w + (l >> 4) * 4 + q) * 136 + c * 16 + lr] = (_Float16)(acc[c][q] * dv[q]);
    __syncthreads();
    f16x2* Hv = (f16x2*)H;
    #pragma unroll
    for (int i = 0; i < 16; i++) {
        int gi = t + i * 256;            // 4096 half2
        int r = gi >> 6, cp = gi & 63;
        int gr = row0 + r;
        if (gr < N) Hv[(size_t)gr * 64 + cp] = *(f16x2*)&Xs[r * 136 + 2 * cp];
    }
}

// ---------------- layer1 aggregate + bias + relu + GEMM2 fused ----------------
// one WAVE per node; lane l = channels 2l,2l+1. Gather unrolled x8 for MLP.
__global__ __launch_bounds__(256) void k_layer1(const _Float16* __restrict__ h,
                                                const int* __restrict__ csr,
                                                const int* __restrict__ row_start,
                                                const float* __restrict__ dinv,
                                                const float* __restrict__ b1,
                                                const float* __restrict__ W2,
                                                float* __restrict__ h2, int N) {
    int n = (blockIdx.x * 256 + threadIdx.x) >> 6;
    int l = threadIdx.x & 63;
    if (n >= N) return;
    const f16x2* hv = (const f16x2*)h;
    float dn = dinv[n];
    f16x2 self = hv[(size_t)n * 64 + l];
    float acc0 = (float)self.x, acc1 = (float)self.y;
    int base = row_start[n];
    int cnt = row_start[n + 1] - base;
    for (int c0 = 0; c0 < cnt; c0 += 64) {
        int m = cnt - c0; if (m > 64) m = 64;
        int idx = (c0 + l < cnt) ? csr[base + c0 + l] : 0;
        int j = 0;
        int jm = m & ~7;
        for (; j < jm; j += 8) {         // 8 independent 256B row-gathers in flight
            int s0 = __shfl(idx, j + 0), s1 = __shfl(idx, j + 1);
            int s2 = __shfl(idx, j + 2), s3 = __shfl(idx, j + 3);
            int s4 = __shfl(idx, j + 4), s5 = __shfl(idx, j + 5);
            int s6 = __shfl(idx, j + 6), s7 = __shfl(idx, j + 7);
            f16x2 v0 = hv[(size_t)s0 * 64 + l];
            f16x2 v1 = hv[(size_t)s1 * 64 + l];
            f16x2 v2 = hv[(size_t)s2 * 64 + l];
            f16x2 v3 = hv[(size_t)s3 * 64 + l];
            f16x2 v4 = hv[(size_t)s4 * 64 + l];
            f16x2 v5 = hv[(size_t)s5 * 64 + l];
            f16x2 v6 = hv[(size_t)s6 * 64 + l];
            f16x2 v7 = hv[(size_t)s7 * 64 + l];
            acc0 += (float)v0.x; acc1 += (float)v0.y;
            acc0 += (float)v1.x; acc1 += (float)v1.y;
            acc0 += (float)v2.x; acc1 += (float)v2.y;
            acc0 += (float)v3.x; acc1 += (float)v3.y;
            acc0 += (float)v4.x; acc1 += (float)v4.y;
            acc0 += (float)v5.x; acc1 += (float)v5.y;
            acc0 += (float)v6.x; acc1 += (float)v6.y;
            acc0 += (float)v7.x; acc1 += (float)v7.y;
        }
        for (; j < m; ++j) {
            int s = __shfl(idx, j);
            f16x2 v = hv[(size_t)s * 64 + l];
            acc0 += (float)v.x; acc1 += (float)v.y;
        }
    }
    float2 bb = ((const float2*)b1)[l];
    float v0 = fmaxf(fmaf(dn, acc0, bb.x), 0.f);
    float v1 = fmaxf(fmaf(dn, acc1, bb.y), 0.f);
    float4 w2 = ((const float4*)W2)[l];  // rows 2l,2l+1 of W2[128][2]
    float p0 = fmaf(v0, w2.x, v1 * w2.z);
    float p1 = fmaf(v0, w2.y, v1 * w2.w);
    #pragma unroll
    for (int off = 32; off; off >>= 1) {
        p0 += __shfl_xor(p0, off);
        p1 += __shfl_xor(p1, off);
    }
    if (l == 0) ((float2*)h2)[n] = make_float2(p0 * dn, p1 * dn);  // pre-scaled by dinv[n]
}

// ---------------- layer2 aggregate + global mean pool accumulate ----------------
__global__ __launch_bounds__(256) void k_layer2_pool(const float* __restrict__ h2,
                                                     const int* __restrict__ csr,
                                                     const int* __restrict__ row_start,
                                                     const float* __restrict__ dinv,
                                                     const int* __restrict__ batch,
                                                     float* __restrict__ gsum,
                                                     int* __restrict__ gcnt, int N) {
    __shared__ float ssum[2 * NGRAPH];
    __shared__ int scnt[NGRAPH];
    int t = threadIdx.x;
    if (t < 2 * NGRAPH) ssum[t] = 0.f;
    if (t < NGRAPH) scnt[t] = 0;
    __syncthreads();
    int n = blockIdx.x * blockDim.x + t;
    if (n < N) {
        const float2* h2v = (const float2*)h2;
        float dn = dinv[n];
        float2 a = h2v[n];               // self term (already *dinv[n])
        int base = row_start[n], end = row_start[n + 1];
        for (int e = base; e < end; e++) {
            float2 v = h2v[csr[e]];
            a.x += v.x;
            a.y += v.y;
        }
        a.x *= dn;
        a.y *= dn;
        int g = batch[n];
        atomicAdd(&ssum[g * 2 + 0], a.x);
        atomicAdd(&ssum[g * 2 + 1], a.y);
        atomicAdd(&scnt[g], 1);
    }
    __syncthreads();
    if (t < 2 * NGRAPH) atomicAdd(&gsum[t], ssum[t]);
    if (t < NGRAPH) atomicAdd(&gcnt[t], scnt[t]);
}

__global__ void k_final(const float* __restrict__ gsum, const int* __restrict__ gcnt,
                        const float* __restrict__ b2, float* __restrict__ out) {
    int t = threadIdx.x;   // 0..127
    if (t < 2 * NGRAPH) {
        int g = t >> 1, c = t & 1;
        float cnt = fmaxf((float)gcnt[g], 1.f);
        out[t] = gsum[t] / cnt + b2[c];
    }
}

extern "C" void kernel_launch(void* const* d_in, const int* in_sizes, int n_in,
                              void* d_out, int out_size, void* d_ws, size_t ws_size,
                              hipStream_t stream) {
    const float* x     = (const float*)d_in[0];
    const int*   ei    = (const int*)d_in[1];
    const int*   batch = (const int*)d_in[2];
    const float* W1    = (const float*)d_in[3];
    const float* b1    = (const float*)d_in[4];
    const float* W2    = (const float*)d_in[5];
    const float* b2    = (const float*)d_in[6];
    float* out = (float*)d_out;

    int N = in_sizes[0] / CH;    // 50000
    int E = in_sizes[1] / 2;     // 800000
    int NB = (N + 127) / 128;    // 391 buckets
    const int* esrc = ei;
    const int* edst = ei + E;

    char* w = (char*)d_ws;
    auto alloc = [&](size_t bytes) -> void* {
        void* p = (void*)w;
        w += (bytes + 255) & ~(size_t)255;
        return p;
    };
    _Float16* h      = (_Float16*)alloc((size_t)N * CH * sizeof(_Float16));  // 12.8 MB
    int* deg         = (int*)  alloc((size_t)N * sizeof(int));
    float* dinv      = (float*)alloc((size_t)N * sizeof(float));
    int* row_start   = (int*)  alloc((size_t)(N + 1) * sizeof(int));
    int* csr         = (int*)  alloc((size_t)E * sizeof(int));
    float* h2        = (float*)alloc((size_t)N * 2 * sizeof(float));
    int* bcur8       = (int*)  alloc((size_t)NB * NCOPY * sizeof(int));
    int* bsum        = (int*)  alloc(256 * sizeof(int));
    int* boff        = (int*)  alloc(256 * sizeof(int));
    float* gsum      = (float*)alloc(128 * sizeof(float));
    int* gcnt        = (int*)  alloc(64 * sizeof(int));
    // bin buffer aliases h: tmp (4.8 MB) is dead before k_gemm1 writes h (stream order)
    unsigned int* tmp = (unsigned int*)h;

    int nbN = (N + 255) / 256;     // 196 (<=256 so single-block scan_b works)
    int NCHUNK = 256;              // k_bin blocks
    int EPB = (E + NCHUNK - 1) / NCHUNK;   // 3125 edges per block

    k_init  <<<nbN, 256, 0, stream>>>(bcur8, row_start, gsum, gcnt, NB, N, E);
    k_bin   <<<NCHUNK, 256, 0, stream>>>(esrc, edst, bcur8, tmp, E, EPB);
    k_hist  <<<NB,  256, 0, stream>>>(tmp, bcur8, deg, dinv, N);
    k_scan_a<<<nbN, 256, 0, stream>>>(deg, row_start, bsum, N);
    k_scan_b<<<1,   256, 0, stream>>>(bsum, boff, nbN);
    k_scan_c<<<nbN, 256, 0, stream>>>(row_start, boff, N);
    k_place <<<NB,  256, 0, stream>>>(tmp, bcur8, row_start, csr, N);
    k_gemm1 <<<(N + 63) / 64, 256, 0, stream>>>(x, W1, dinv, h, N);
    k_layer1<<<(N * 64 + 255) / 256, 256, 0, stream>>>(h, csr, row_start, dinv, b1, W2, h2, N);
    k_layer2_pool<<<nbN, 256, 0, stream>>>(h2, csr, row_start, dinv, batch, gsum, gcnt, N);
    k_final <<<1, 128, 0, stream>>>(gsum, gcnt, b2, out);
}

// Round 7
// 174.884 us; speedup vs baseline: 2.5601x; 1.0606x over previous
//
#include <hip/hip_runtime.h>

// GCN 2-layer forward on MI355X (gfx950).
// R7: collapse dispatch chain 11 -> 8 kernels. k_bsum scans 391 bucket totals
// (1 block); k_build fuses hist + dinv + intra-bucket scan + row_start + csr
// scatter (one tmp read instead of two). W1^T fp16 precomputed in k_init so
// k_gemm1 stages W by straight copy. k_bin/k_layer1/k_layer2_pool unchanged.

#define NGRAPH 64
#define CH 128
#define BSUB 384          // per-(bucket,copy) capacity: lambda=256, +8 sigma
#define NCOPY 8
#define BCAPT (BSUB * NCOPY)   // 3072 slots per bucket

typedef float f32x4 __attribute__((ext_vector_type(4)));
typedef _Float16 f16x8 __attribute__((ext_vector_type(8)));
typedef _Float16 f16x4 __attribute__((ext_vector_type(4)));
typedef _Float16 f16x2 __attribute__((ext_vector_type(2)));

// ---------------- init: zero counters + W1^T fp16 ----------------
__global__ void k_init(int* __restrict__ bcur8, int* __restrict__ row_start,
                       float* __restrict__ gsum, int* __restrict__ gcnt,
                       const float* __restrict__ W1, _Float16* __restrict__ w1t,
                       int NB, int N, int E) {
    int i = blockIdx.x * blockDim.x + threadIdx.x;
    if (i < NB * NCOPY) bcur8[i] = 0;
    if (i == 0) row_start[N] = E;          // sentinel (non-self edge total)
    if (i < 2 * NGRAPH) gsum[i] = 0.f;
    if (i < NGRAPH) gcnt[i] = 0;
    if (i < CH * CH) {                     // w1t[c][k] = W1[k][c]
        int k = i >> 7, c = i & 127;
        w1t[c * CH + k] = (_Float16)W1[i];
    }
}

// ---------------- pass 1: chunked block-aggregated binning ----------------
__global__ __launch_bounds__(256) void k_bin(const int* __restrict__ src,
                                             const int* __restrict__ dst,
                                             int* __restrict__ bcur8,
                                             unsigned int* __restrict__ tmp,
                                             int E, int EPB) {
    __shared__ int hist[512];
    __shared__ int gbase[512];
    __shared__ int cur[512];
    int t = threadIdx.x;
    int e0 = blockIdx.x * EPB;
    int e1 = min(E, e0 + EPB);
    for (int i = t; i < 512; i += 256) { hist[i] = 0; cur[i] = 0; }
    __syncthreads();
    for (int e = e0 + t; e < e1; e += 256)
        atomicAdd(&hist[dst[e] >> 7], 1);          // LDS atomic, ~8 deep
    __syncthreads();
    int copy = blockIdx.x & (NCOPY - 1);
    for (int b = t; b < 512; b += 256) {
        int hc = hist[b];
        if (hc) gbase[b] = atomicAdd(&bcur8[b * NCOPY + copy], hc);  // 1 per bucket
    }
    __syncthreads();
    for (int e = e0 + t; e < e1; e += 256) {
        int d = dst[e];
        int b = d >> 7;
        int li = atomicAdd(&cur[b], 1);            // LDS cursor
        int pos = gbase[b] + li;
        if (pos < BSUB)
            tmp[(size_t)b * BCAPT + copy * BSUB + pos] =
                ((unsigned)(d & 127) << 25) | (unsigned)src[e];
    }
}

// ---------------- bucket-total exclusive scan (1 block, 512 thr) ----------------
__global__ __launch_bounds__(512) void k_bsum(const int* __restrict__ bcur8,
                                              int* __restrict__ bbase, int NB) {
    __shared__ int tmp[512];
    int t = threadIdx.x;
    int v = 0;
    if (t < NB)
        for (int c = 0; c < NCOPY; c++) v += min(bcur8[t * NCOPY + c], BSUB);
    int val = v;
    tmp[t] = val;
    __syncthreads();
    for (int off = 1; off < 512; off <<= 1) {
        int add = (t >= off) ? tmp[t - off] : 0;
        __syncthreads();
        val += add;
        tmp[t] = val;
        __syncthreads();
    }
    if (t < NB) bbase[t] = val - v;        // exclusive
}

// ---------------- fused build: hist + dinv + row_start + csr ----------------
__global__ __launch_bounds__(256) void k_build(const unsigned int* __restrict__ tmp,
                                               const int* __restrict__ bcur8,
                                               const int* __restrict__ bbase,
                                               int* __restrict__ row_start,
                                               float* __restrict__ dinv,
                                               int* __restrict__ csr, int N) {
    __shared__ int hist[128];
    __shared__ int scan[128];
    __shared__ int lcur[128];
    int b = blockIdx.x, t = threadIdx.x;
    if (t < 128) hist[t] = 0;
    __syncthreads();
    const unsigned int* tb = tmp + (size_t)b * BCAPT;
    for (int c = 0; c < NCOPY; c++) {
        int cnt = min(bcur8[b * NCOPY + c], BSUB);
        const unsigned int* tp = tb + c * BSUB;
        for (int e = t; e < cnt; e += 256) atomicAdd(&hist[tp[e] >> 25], 1);
    }
    __syncthreads();
    // exclusive scan of hist[0..127] (first 128 threads; barriers uniform)
    int val = 0, v = 0;
    if (t < 128) { v = hist[t]; val = v; scan[t] = val; }
    __syncthreads();
    for (int off = 1; off < 128; off <<= 1) {
        int add = (t >= off && t < 128) ? scan[t - off] : 0;
        __syncthreads();
        if (t < 128) { val += add; scan[t] = val; }
        __syncthreads();
    }
    int base = bbase[b];
    if (t < 128) {
        int excl = val - v;
        lcur[t] = excl;
        int n = b * 128 + t;
        if (n < N) {
            row_start[n] = base + excl;
            dinv[n] = rsqrtf((float)(v + 1));   // + self-loop
        }
    }
    __syncthreads();
    for (int c = 0; c < NCOPY; c++) {
        int cnt = min(bcur8[b * NCOPY + c], BSUB);
        const unsigned int* tp = tb + c * BSUB;
        for (int e = t; e < cnt; e += 256) {
            unsigned p = tp[e];
            int pos = atomicAdd(&lcur[p >> 25], 1);   // LDS atomic
            csr[base + pos] = (int)(p & 0x01FFFFFFu);
        }
    }
}

// ---------------- GEMM1 (MFMA fp16): h[n] = fp16((x[n] @ W1) * dinv[n]) ----------------
__global__ __launch_bounds__(256) void k_gemm1(const float* __restrict__ X,
                                               const _Float16* __restrict__ w1t,
                                               const float* __restrict__ dinv,
                                               _Float16* __restrict__ H, int N) {
    __shared__ _Float16 Xs[64 * 136];   // 272B row stride (16B-aligned)
    __shared__ _Float16 Ws[128 * 136];  // Ws[col][k]
    int t = threadIdx.x;
    int row0 = blockIdx.x * 64;
    const float4* Xv = (const float4*)X;

    #pragma unroll
    for (int i = 0; i < 8; i++) {
        int gi = t + i * 256;            // 2048 float4
        int r = gi >> 5, c4 = gi & 31;
        int gr = row0 + r;
        float4 v = (gr < N) ? Xv[(size_t)gr * 32 + c4] : make_float4(0.f, 0.f, 0.f, 0.f);
        f16x4 hv = {(_Float16)v.x, (_Float16)v.y, (_Float16)v.z, (_Float16)v.w};
        *(f16x4*)&Xs[r * 136 + 4 * c4] = hv;
    }
    #pragma unroll
    for (int i = 0; i < 8; i++) {        // straight copy of w1t (32 KB)
        int gi = t + i * 256;            // 2048 f16x8 chunks: row=gi>>4, chunk=gi&15
        int r = gi >> 4, cc = gi & 15;
        f16x8 vv = *(const f16x8*)&w1t[r * CH + cc * 8];
        *(f16x8*)&Ws[r * 136 + cc * 8] = vv;
    }
    __syncthreads();

    int w = t >> 6, l = t & 63;
    int r0w = w * 16;
    int lr = l & 15, lk = (l >> 4) * 8;
    f32x4 acc[8] = {};
    #pragma unroll
    for (int k0 = 0; k0 < 128; k0 += 32) {
        f16x8 a = *(const f16x8*)&Xs[(r0w + lr) * 136 + k0 + lk];
        #pragma unroll
        for (int c = 0; c < 8; c++) {
            f16x8 bf = *(const f16x8*)&Ws[(c * 16 + lr) * 136 + k0 + lk];
            acc[c] = __builtin_amdgcn_mfma_f32_16x16x32_f16(a, bf, acc[c], 0, 0, 0);
        }
    }
    float dv[4];
    #pragma unroll
    for (int q = 0; q < 4; q++) {
        int gr = row0 + r0w + (l >> 4) * 4 + q;
        dv[q] = (gr < N) ? dinv[gr] : 0.f;
    }
    __syncthreads();
    #pragma unroll
    for (int c = 0; c < 8; c++)
        #pragma unroll
        for (int q = 0; q < 4; q++)      // C/D map: col=lane&15, row=(lane>>4)*4+q
            Xs[(r0w + (l >> 4) * 4 + q) * 136 + c * 16 + lr] = (_Float16)(acc[c][q] * dv[q]);
    __syncthreads();
    f16x2* Hv = (f16x2*)H;
    #pragma unroll
    for (int i = 0; i < 16; i++) {
        int gi = t + i * 256;            // 4096 half2
        int r = gi >> 6, cp = gi & 63;
        int gr = row0 + r;
        if (gr < N) Hv[(size_t)gr * 64 + cp] = *(f16x2*)&Xs[r * 136 + 2 * cp];
    }
}

// ---------------- layer1 aggregate + bias + relu + GEMM2 fused ----------------
// one WAVE per node; lane l = channels 2l,2l+1. Gather unrolled x8 for MLP.
__global__ __launch_bounds__(256) void k_layer1(const _Float16* __restrict__ h,
                                                const int* __restrict__ csr,
                                                const int* __restrict__ row_start,
                                                const float* __restrict__ dinv,
                                                const float* __restrict__ b1,
                                                const float* __restrict__ W2,
                                                float* __restrict__ h2, int N) {
    int n = (blockIdx.x * 256 + threadIdx.x) >> 6;
    int l = threadIdx.x & 63;
    if (n >= N) return;
    const f16x2* hv = (const f16x2*)h;
    float dn = dinv[n];
    f16x2 self = hv[(size_t)n * 64 + l];
    float acc0 = (float)self.x, acc1 = (float)self.y;
    int base = row_start[n];
    int cnt = row_start[n + 1] - base;
    for (int c0 = 0; c0 < cnt; c0 += 64) {
        int m = cnt - c0; if (m > 64) m = 64;
        int idx = (c0 + l < cnt) ? csr[base + c0 + l] : 0;
        int j = 0;
        int jm = m & ~7;
        for (; j < jm; j += 8) {         // 8 independent 256B row-gathers in flight
            int s0 = __shfl(idx, j + 0), s1 = __shfl(idx, j + 1);
            int s2 = __shfl(idx, j + 2), s3 = __shfl(idx, j + 3);
            int s4 = __shfl(idx, j + 4), s5 = __shfl(idx, j + 5);
            int s6 = __shfl(idx, j + 6), s7 = __shfl(idx, j + 7);
            f16x2 v0 = hv[(size_t)s0 * 64 + l];
            f16x2 v1 = hv[(size_t)s1 * 64 + l];
            f16x2 v2 = hv[(size_t)s2 * 64 + l];
            f16x2 v3 = hv[(size_t)s3 * 64 + l];
            f16x2 v4 = hv[(size_t)s4 * 64 + l];
            f16x2 v5 = hv[(size_t)s5 * 64 + l];
            f16x2 v6 = hv[(size_t)s6 * 64 + l];
            f16x2 v7 = hv[(size_t)s7 * 64 + l];
            acc0 += (float)v0.x; acc1 += (float)v0.y;
            acc0 += (float)v1.x; acc1 += (float)v1.y;
            acc0 += (float)v2.x; acc1 += (float)v2.y;
            acc0 += (float)v3.x; acc1 += (float)v3.y;
            acc0 += (float)v4.x; acc1 += (float)v4.y;
            acc0 += (float)v5.x; acc1 += (float)v5.y;
            acc0 += (float)v6.x; acc1 += (float)v6.y;
            acc0 += (float)v7.x; acc1 += (float)v7.y;
        }
        for (; j < m; ++j) {
            int s = __shfl(idx, j);
            f16x2 v = hv[(size_t)s * 64 + l];
            acc0 += (float)v.x; acc1 += (float)v.y;
        }
    }
    float2 bb = ((const float2*)b1)[l];
    float v0 = fmaxf(fmaf(dn, acc0, bb.x), 0.f);
    float v1 = fmaxf(fmaf(dn, acc1, bb.y), 0.f);
    float4 w2 = ((const float4*)W2)[l];  // rows 2l,2l+1 of W2[128][2]
    float p0 = fmaf(v0, w2.x, v1 * w2.z);
    float p1 = fmaf(v0, w2.y, v1 * w2.w);
    #pragma unroll
    for (int off = 32; off; off >>= 1) {
        p0 += __shfl_xor(p0, off);
        p1 += __shfl_xor(p1, off);
    }
    if (l == 0) ((float2*)h2)[n] = make_float2(p0 * dn, p1 * dn);  // pre-scaled by dinv[n]
}

// ---------------- layer2 aggregate + global mean pool accumulate ----------------
__global__ __launch_bounds__(256) void k_layer2_pool(const float* __restrict__ h2,
                                                     const int* __restrict__ csr,
                                                     const int* __restrict__ row_start,
                                                     const float* __restrict__ dinv,
                                                     const int* __restrict__ batch,
                                                     float* __restrict__ gsum,
                                                     int* __restrict__ gcnt, int N) {
    __shared__ float ssum[2 * NGRAPH];
    __shared__ int scnt[NGRAPH];
    int t = threadIdx.x;
    if (t < 2 * NGRAPH) ssum[t] = 0.f;
    if (t < NGRAPH) scnt[t] = 0;
    __syncthreads();
    int n = blockIdx.x * blockDim.x + t;
    if (n < N) {
        const float2* h2v = (const float2*)h2;
        float dn = dinv[n];
        float2 a = h2v[n];               // self term (already *dinv[n])
        int base = row_start[n], end = row_start[n + 1];
        for (int e = base; e < end; e++) {
            float2 v = h2v[csr[e]];
            a.x += v.x;
            a.y += v.y;
        }
        a.x *= dn;
        a.y *= dn;
        int g = batch[n];
        atomicAdd(&ssum[g * 2 + 0], a.x);
        atomicAdd(&ssum[g * 2 + 1], a.y);
        atomicAdd(&scnt[g], 1);
    }
    __syncthreads();
    if (t < 2 * NGRAPH) atomicAdd(&gsum[t], ssum[t]);
    if (t < NGRAPH) atomicAdd(&gcnt[t], scnt[t]);
}

__global__ void k_final(const float* __restrict__ gsum, const int* __restrict__ gcnt,
                        const float* __restrict__ b2, float* __restrict__ out) {
    int t = threadIdx.x;   // 0..127
    if (t < 2 * NGRAPH) {
        int g = t >> 1, c = t & 1;
        float cnt = fmaxf((float)gcnt[g], 1.f);
        out[t] = gsum[t] / cnt + b2[c];
    }
}

extern "C" void kernel_launch(void* const* d_in, const int* in_sizes, int n_in,
                              void* d_out, int out_size, void* d_ws, size_t ws_size,
                              hipStream_t stream) {
    const float* x     = (const float*)d_in[0];
    const int*   ei    = (const int*)d_in[1];
    const int*   batch = (const int*)d_in[2];
    const float* W1    = (const float*)d_in[3];
    const float* b1    = (const float*)d_in[4];
    const float* W2    = (const float*)d_in[5];
    const float* b2    = (const float*)d_in[6];
    float* out = (float*)d_out;

    int N = in_sizes[0] / CH;    // 50000
    int E = in_sizes[1] / 2;     // 800000
    int NB = (N + 127) / 128;    // 391 buckets (must be <= 512 for k_bsum)
    const int* esrc = ei;
    const int* edst = ei + E;

    char* w = (char*)d_ws;
    auto alloc = [&](size_t bytes) -> void* {
        void* p = (void*)w;
        w += (bytes + 255) & ~(size_t)255;
        return p;
    };
    _Float16* h      = (_Float16*)alloc((size_t)N * CH * sizeof(_Float16));  // 12.8 MB
    float* dinv      = (float*)alloc((size_t)N * sizeof(float));
    int* row_start   = (int*)  alloc((size_t)(N + 1) * sizeof(int));
    int* csr         = (int*)  alloc((size_t)E * sizeof(int));
    float* h2        = (float*)alloc((size_t)N * 2 * sizeof(float));
    int* bcur8       = (int*)  alloc((size_t)NB * NCOPY * sizeof(int));
    int* bbase       = (int*)  alloc((size_t)NB * sizeof(int));
    _Float16* w1t    = (_Float16*)alloc((size_t)CH * CH * sizeof(_Float16));
    float* gsum      = (float*)alloc(128 * sizeof(float));
    int* gcnt        = (int*)  alloc(64 * sizeof(int));
    // bin buffer aliases h: tmp (4.8 MB) is dead before k_gemm1 writes h (stream order)
    unsigned int* tmp = (unsigned int*)h;

    int nbN = (N + 255) / 256;     // 196
    int NCHUNK = 256;              // k_bin blocks
    int EPB = (E + NCHUNK - 1) / NCHUNK;   // 3125 edges per block

    k_init  <<<64, 256, 0, stream>>>(bcur8, row_start, gsum, gcnt, W1, w1t, NB, N, E);
    k_bin   <<<NCHUNK, 256, 0, stream>>>(esrc, edst, bcur8, tmp, E, EPB);
    k_bsum  <<<1, 512, 0, stream>>>(bcur8, bbase, NB);
    k_build <<<NB, 256, 0, stream>>>(tmp, bcur8, bbase, row_start, dinv, csr, N);
    k_gemm1 <<<(N + 63) / 64, 256, 0, stream>>>(x, w1t, dinv, h, N);
    k_layer1<<<(N * 64 + 255) / 256, 256, 0, stream>>>(h, csr, row_start, dinv, b1, W2, h2, N);
    k_layer2_pool<<<nbN, 256, 0, stream>>>(h2, csr, row_start, dinv, batch, gsum, gcnt, N);
    k_final <<<1, 128, 0, stream>>>(gsum, gcnt, b2, out);
}

// Round 9
// 169.657 us; speedup vs baseline: 2.6389x; 1.0308x over previous
//
#include <hip/hip_runtime.h>

// GCN 2-layer forward on MI355X (gfx950).
// R8 resubmit (bench never ran: GPU acquisition timeout). 6 dispatches.
// Padded-CSR (neighbor lists padded to x8 with sentinel row N => layer1 gather
// is pure 8-deep batches, no serial tail; fixed-stride bucket regions kill
// k_bsum/global scan). rs2=int2{start,cnt}. k_final fused into k_layer2_pool
// via done-counter + fence + atomic reads.

#define NGRAPH 64
#define CH 128
#define BSUB 384            // per-(bucket,copy) capacity: lambda=256, +8 sigma
#define NCOPY 8
#define BCAPT (BSUB * NCOPY)    // 3072 bin slots per bucket
#define CSTR 4096               // csr region stride per bucket (3968 max used)

typedef float f32x4 __attribute__((ext_vector_type(4)));
typedef _Float16 f16x8 __attribute__((ext_vector_type(8)));
typedef _Float16 f16x4 __attribute__((ext_vector_type(4)));
typedef _Float16 f16x2 __attribute__((ext_vector_type(2)));

// ---------------- init: zero counters, h2 sentinel, W1^T fp16 ----------------
__global__ void k_init(int* __restrict__ bcur8, float* __restrict__ gsum,
                       int* __restrict__ gcnt, int* __restrict__ done,
                       float* __restrict__ h2,
                       const float* __restrict__ W1, _Float16* __restrict__ w1t,
                       int NB, int N) {
    int i = blockIdx.x * blockDim.x + threadIdx.x;
    if (i < NB * NCOPY) bcur8[i] = 0;
    if (i < 2 * NGRAPH) gsum[i] = 0.f;
    if (i < NGRAPH) gcnt[i] = 0;
    if (i == 0) *done = 0;
    if (i < 2) h2[2 * N + i] = 0.f;        // zero sentinel row of h2
    if (i < CH * CH) {                     // w1t[c][k] = W1[k][c]
        int k = i >> 7, c = i & 127;
        w1t[c * CH + k] = (_Float16)W1[i];
    }
}

// ---------------- pass 1: chunked block-aggregated binning ----------------
__global__ __launch_bounds__(256) void k_bin(const int* __restrict__ src,
                                             const int* __restrict__ dst,
                                             int* __restrict__ bcur8,
                                             unsigned int* __restrict__ tmp,
                                             int E, int EPB) {
    __shared__ int hist[512];
    __shared__ int gbase[512];
    __shared__ int cur[512];
    int t = threadIdx.x;
    int e0 = blockIdx.x * EPB;
    int e1 = min(E, e0 + EPB);
    for (int i = t; i < 512; i += 256) { hist[i] = 0; cur[i] = 0; }
    __syncthreads();
    for (int e = e0 + t; e < e1; e += 256)
        atomicAdd(&hist[dst[e] >> 7], 1);          // LDS atomic, ~8 deep
    __syncthreads();
    int copy = blockIdx.x & (NCOPY - 1);
    for (int b = t; b < 512; b += 256) {
        int hc = hist[b];
        if (hc) gbase[b] = atomicAdd(&bcur8[b * NCOPY + copy], hc);  // 1 per bucket
    }
    __syncthreads();
    for (int e = e0 + t; e < e1; e += 256) {
        int d = dst[e];
        int b = d >> 7;
        int li = atomicAdd(&cur[b], 1);            // LDS cursor
        int pos = gbase[b] + li;
        if (pos < BSUB)
            tmp[(size_t)b * BCAPT + copy * BSUB + pos] =
                ((unsigned)(d & 127) << 25) | (unsigned)src[e];
    }
}

// ---------------- fused build: hist + dinv + rs2 + padded csr ----------------
__global__ __launch_bounds__(256) void k_build(const unsigned int* __restrict__ tmp,
                                               const int* __restrict__ bcur8,
                                               int2* __restrict__ rs2,
                                               float* __restrict__ dinv,
                                               int* __restrict__ csr, int N) {
    __shared__ int hist[128];
    __shared__ int scan[128];
    __shared__ int lcur[128];
    int b = blockIdx.x, t = threadIdx.x;
    if (t < 128) hist[t] = 0;
    __syncthreads();
    const unsigned int* tb = tmp + (size_t)b * BCAPT;
    for (int c = 0; c < NCOPY; c++) {
        int cnt = min(bcur8[b * NCOPY + c], BSUB);
        const unsigned int* tp = tb + c * BSUB;
        for (int e = t; e < cnt; e += 256) atomicAdd(&hist[tp[e] >> 25], 1);
    }
    __syncthreads();
    // exclusive scan of PADDED counts (first 128 threads; uniform barriers)
    int val = 0, v = 0, pv = 0;
    if (t < 128) { v = hist[t]; pv = (v + 7) & ~7; val = pv; scan[t] = val; }
    __syncthreads();
    for (int off = 1; off < 128; off <<= 1) {
        int add = (t >= off && t < 128) ? scan[t - off] : 0;
        __syncthreads();
        if (t < 128) { val += add; scan[t] = val; }
        __syncthreads();
    }
    int base = b * CSTR;
    if (t < 128) {
        int excl = val - pv;               // padded exclusive offset
        lcur[t] = excl;
        int n = b * 128 + t;
        if (n < N) {
            rs2[n] = make_int2(base + excl, pv);
            dinv[n] = rsqrtf((float)(v + 1));   // + self-loop (real degree)
            for (int e = v; e < pv; e++) csr[base + excl + e] = N;  // pad -> sentinel
        }
    }
    __syncthreads();
    for (int c = 0; c < NCOPY; c++) {
        int cnt = min(bcur8[b * NCOPY + c], BSUB);
        const unsigned int* tp = tb + c * BSUB;
        for (int e = t; e < cnt; e += 256) {
            unsigned p = tp[e];
            int pos = atomicAdd(&lcur[p >> 25], 1);   // LDS atomic
            csr[base + pos] = (int)(p & 0x01FFFFFFu);
        }
    }
}

// ---------------- GEMM1 (MFMA fp16): h[n] = fp16((x[n] @ W1) * dinv[n]) ----------------
// rows >= N store zeros (sentinel row N used by padded gather).
__global__ __launch_bounds__(256) void k_gemm1(const float* __restrict__ X,
                                               const _Float16* __restrict__ w1t,
                                               const float* __restrict__ dinv,
                                               _Float16* __restrict__ H, int N) {
    __shared__ _Float16 Xs[64 * 136];   // 272B row stride (16B-aligned)
    __shared__ _Float16 Ws[128 * 136];  // Ws[col][k]
    int t = threadIdx.x;
    int row0 = blockIdx.x * 64;
    const float4* Xv = (const float4*)X;

    #pragma unroll
    for (int i = 0; i < 8; i++) {
        int gi = t + i * 256;            // 2048 float4
        int r = gi >> 5, c4 = gi & 31;
        int gr = row0 + r;
        float4 v = (gr < N) ? Xv[(size_t)gr * 32 + c4] : make_float4(0.f, 0.f, 0.f, 0.f);
        f16x4 hv = {(_Float16)v.x, (_Float16)v.y, (_Float16)v.z, (_Float16)v.w};
        *(f16x4*)&Xs[r * 136 + 4 * c4] = hv;
    }
    #pragma unroll
    for (int i = 0; i < 8; i++) {        // straight copy of w1t (32 KB)
        int gi = t + i * 256;
        int r = gi >> 4, cc = gi & 15;
        f16x8 vv = *(const f16x8*)&w1t[r * CH + cc * 8];
        *(f16x8*)&Ws[r * 136 + cc * 8] = vv;
    }
    __syncthreads();

    int w = t >> 6, l = t & 63;
    int r0w = w * 16;
    int lr = l & 15, lk = (l >> 4) * 8;
    f32x4 acc[8] = {};
    #pragma unroll
    for (int k0 = 0; k0 < 128; k0 += 32) {
        f16x8 a = *(const f16x8*)&Xs[(r0w + lr) * 136 + k0 + lk];
        #pragma unroll
        for (int c = 0; c < 8; c++) {
            f16x8 bf = *(const f16x8*)&Ws[(c * 16 + lr) * 136 + k0 + lk];
            acc[c] = __builtin_amdgcn_mfma_f32_16x16x32_f16(a, bf, acc[c], 0, 0, 0);
        }
    }
    float dv[4];
    #pragma unroll
    for (int q = 0; q < 4; q++) {
        int gr = row0 + r0w + (l >> 4) * 4 + q;
        dv[q] = (gr < N) ? dinv[gr] : 0.f;   // rows >= N -> zeros
    }
    __syncthreads();
    #pragma unroll
    for (int c = 0; c < 8; c++)
        #pragma unroll
        for (int q = 0; q < 4; q++)      // C/D map: col=lane&15, row=(lane>>4)*4+q
            Xs[(r0w + (l >> 4) * 4 + q) * 136 + c * 16 + lr] = (_Float16)(acc[c][q] * dv[q]);
    __syncthreads();
    f16x2* Hv = (f16x2*)H;
    #pragma unroll
    for (int i = 0; i < 16; i++) {
        int gi = t + i * 256;            // 4096 half2 (all rows stored, incl. zero pad)
        int r = gi >> 6, cp = gi & 63;
        int gr = row0 + r;
        Hv[(size_t)gr * 64 + cp] = *(f16x2*)&Xs[r * 136 + 2 * cp];
    }
}

// ---------------- layer1 aggregate + bias + relu + GEMM2 fused ----------------
// one WAVE per node; lane l = channels 2l,2l+1. Padded lists: pure 8-deep batches.
__global__ __launch_bounds__(256) void k_layer1(const _Float16* __restrict__ h,
                                                const int* __restrict__ csr,
                                                const int2* __restrict__ rs2,
                                                const float* __restrict__ dinv,
                                                const float* __restrict__ b1,
                                                const float* __restrict__ W2,
                                                float* __restrict__ h2, int N) {
    int n = (blockIdx.x * 256 + threadIdx.x) >> 6;
    int l = threadIdx.x & 63;
    if (n >= N) return;
    const f16x2* hv = (const f16x2*)h;
    float dn = dinv[n];
    f16x2 self = hv[(size_t)n * 64 + l];
    float acc0 = (float)self.x, acc1 = (float)self.y;
    int2 rs = rs2[n];
    int base = rs.x, cnt = rs.y;           // cnt is multiple of 8 (padded)
    for (int c0 = 0; c0 < cnt; c0 += 64) {
        int m = cnt - c0; if (m > 64) m = 64;   // multiple of 8
        int idx = csr[base + c0 + l];           // pad slots hold sentinel N
        for (int j = 0; j < m; j += 8) {        // 8 independent gathers in flight
            int s0 = __shfl(idx, j + 0), s1 = __shfl(idx, j + 1);
            int s2 = __shfl(idx, j + 2), s3 = __shfl(idx, j + 3);
            int s4 = __shfl(idx, j + 4), s5 = __shfl(idx, j + 5);
            int s6 = __shfl(idx, j + 6), s7 = __shfl(idx, j + 7);
            f16x2 v0 = hv[(size_t)s0 * 64 + l];
            f16x2 v1 = hv[(size_t)s1 * 64 + l];
            f16x2 v2 = hv[(size_t)s2 * 64 + l];
            f16x2 v3 = hv[(size_t)s3 * 64 + l];
            f16x2 v4 = hv[(size_t)s4 * 64 + l];
            f16x2 v5 = hv[(size_t)s5 * 64 + l];
            f16x2 v6 = hv[(size_t)s6 * 64 + l];
            f16x2 v7 = hv[(size_t)s7 * 64 + l];
            acc0 += (float)v0.x; acc1 += (float)v0.y;
            acc0 += (float)v1.x; acc1 += (float)v1.y;
            acc0 += (float)v2.x; acc1 += (float)v2.y;
            acc0 += (float)v3.x; acc1 += (float)v3.y;
            acc0 += (float)v4.x; acc1 += (float)v4.y;
            acc0 += (float)v5.x; acc1 += (float)v5.y;
            acc0 += (float)v6.x; acc1 += (float)v6.y;
            acc0 += (float)v7.x; acc1 += (float)v7.y;
        }
    }
    float2 bb = ((const float2*)b1)[l];
    float v0 = fmaxf(fmaf(dn, acc0, bb.x), 0.f);
    float v1 = fmaxf(fmaf(dn, acc1, bb.y), 0.f);
    float4 w2 = ((const float4*)W2)[l];  // rows 2l,2l+1 of W2[128][2]
    float p0 = fmaf(v0, w2.x, v1 * w2.z);
    float p1 = fmaf(v0, w2.y, v1 * w2.w);
    #pragma unroll
    for (int off = 32; off; off >>= 1) {
        p0 += __shfl_xor(p0, off);
        p1 += __shfl_xor(p1, off);
    }
    if (l == 0) ((float2*)h2)[n] = make_float2(p0 * dn, p1 * dn);  // pre-scaled by dinv[n]
}

// ---------------- layer2 aggregate + pool + FUSED final ----------------
__global__ __launch_bounds__(256) void k_layer2_pool(const float* __restrict__ h2,
                                                     const int* __restrict__ csr,
                                                     const int2* __restrict__ rs2,
                                                     const float* __restrict__ dinv,
                                                     const int* __restrict__ batch,
                                                     float* __restrict__ gsum,
                                                     int* __restrict__ gcnt,
                                                     int* __restrict__ done,
                                                     const float* __restrict__ b2,
                                                     float* __restrict__ out, int N) {
    __shared__ float ssum[2 * NGRAPH];
    __shared__ int scnt[NGRAPH];
    __shared__ int s_last;
    int t = threadIdx.x;
    if (t < 2 * NGRAPH) ssum[t] = 0.f;
    if (t < NGRAPH) scnt[t] = 0;
    __syncthreads();
    int n = blockIdx.x * blockDim.x + t;
    if (n < N) {
        const float2* h2v = (const float2*)h2;
        float dn = dinv[n];
        float2 a = h2v[n];               // self term (already *dinv[n])
        int2 rs = rs2[n];
        for (int e = rs.x; e < rs.x + rs.y; e++) {   // pad -> h2[N]=0
            float2 v = h2v[csr[e]];
            a.x += v.x;
            a.y += v.y;
        }
        a.x *= dn;
        a.y *= dn;
        int g = batch[n];
        atomicAdd(&ssum[g * 2 + 0], a.x);
        atomicAdd(&ssum[g * 2 + 1], a.y);
        atomicAdd(&scnt[g], 1);
    }
    __syncthreads();
    if (t < 2 * NGRAPH) atomicAdd(&gsum[t], ssum[t]);
    if (t < NGRAPH) atomicAdd(&gcnt[t], scnt[t]);
    // ---- fused final: last block computes out ----
    __syncthreads();
    if (t == 0) {
        __threadfence();
        int r = atomicAdd(done, 1);
        s_last = (r == (int)gridDim.x - 1) ? 1 : 0;
    }
    __syncthreads();
    if (s_last && t < 2 * NGRAPH) {
        int g = t >> 1, c = t & 1;
        float sv = atomicAdd(&gsum[t], 0.f);           // device-coherent read
        float cv = (float)atomicAdd(&gcnt[g], 0);
        out[t] = sv / fmaxf(cv, 1.f) + b2[c];
    }
}

extern "C" void kernel_launch(void* const* d_in, const int* in_sizes, int n_in,
                              void* d_out, int out_size, void* d_ws, size_t ws_size,
                              hipStream_t stream) {
    const float* x     = (const float*)d_in[0];
    const int*   ei    = (const int*)d_in[1];
    const int*   batch = (const int*)d_in[2];
    const float* W1    = (const float*)d_in[3];
    const float* b1    = (const float*)d_in[4];
    const float* W2    = (const float*)d_in[5];
    const float* b2    = (const float*)d_in[6];
    float* out = (float*)d_out;

    int N = in_sizes[0] / CH;    // 50000
    int E = in_sizes[1] / 2;     // 800000
    int NB = (N + 127) / 128;    // 391 buckets
    const int* esrc = ei;
    const int* edst = ei + E;

    char* w = (char*)d_ws;
    auto alloc = [&](size_t bytes) -> void* {
        void* p = (void*)w;
        w += (bytes + 255) & ~(size_t)255;
        return p;
    };
    _Float16* h      = (_Float16*)alloc((size_t)(N + 64) * CH * sizeof(_Float16)); // + pad rows
    float* dinv      = (float*)alloc((size_t)N * sizeof(float));
    int2* rs2        = (int2*) alloc((size_t)N * sizeof(int2));
    int* csr         = (int*)  alloc((size_t)NB * CSTR * sizeof(int));   // 6.4 MB padded
    float* h2        = (float*)alloc((size_t)(N + 1) * 2 * sizeof(float));
    int* bcur8       = (int*)  alloc((size_t)NB * NCOPY * sizeof(int));
    _Float16* w1t    = (_Float16*)alloc((size_t)CH * CH * sizeof(_Float16));
    float* gsum      = (float*)alloc(128 * sizeof(float));
    int* gcnt        = (int*)  alloc(64 * sizeof(int));
    int* done        = (int*)  alloc(256);
    // bin buffer aliases h: tmp (4.8 MB) is dead before k_gemm1 writes h
    unsigned int* tmp = (unsigned int*)h;

    int nbN = (N + 255) / 256;     // 196
    int NCHUNK = 256;              // k_bin blocks
    int EPB = (E + NCHUNK - 1) / NCHUNK;   // 3125 edges per block

    k_init  <<<64, 256, 0, stream>>>(bcur8, gsum, gcnt, done, h2, W1, w1t, NB, N);
    k_bin   <<<NCHUNK, 256, 0, stream>>>(esrc, edst, bcur8, tmp, E, EPB);
    k_build <<<NB, 256, 0, stream>>>(tmp, bcur8, rs2, dinv, csr, N);
    k_gemm1 <<<(N + 63) / 64, 256, 0, stream>>>(x, w1t, dinv, h, N);
    k_layer1<<<(N * 64 + 255) / 256, 256, 0, stream>>>(h, csr, rs2, dinv, b1, W2, h2, N);
    k_layer2_pool<<<nbN, 256, 0, stream>>>(h2, csr, rs2, dinv, batch, gsum, gcnt,
                                           done, b2, out, N);
}